// Round 4
// baseline (332.294 us; speedup 1.0000x reference)
//
#include <hip/hip_runtime.h>

// DeformConv fused pipeline, MI355X gfx950.
// Shapes (hard-coded per reference): B=2, Ci=Co=256, H=W=96.
// R4 changes vs R3 (off_conv 164us @ 1.1 waves/SIMD; dcn_gemm 151us @ 9 waves/CU):
//  - off_conv: 1152 blocks (64px x 4 ci-subchunks/block + LDS reduce), w_off
//    transposed to [ci][ch*9+t] for contiguous uniform loads.
//  - dcn_gemm: BN=32 -> 576 blocks (2.25 blocks/CU), per-thread 2 samples/chunk.
//  - bn_stats float4 loads.

typedef unsigned short ushort_t;
typedef unsigned int uint_t;
typedef __attribute__((ext_vector_type(8))) short bf16x8;
typedef __attribute__((ext_vector_type(4))) float f32x4;
typedef __attribute__((ext_vector_type(2), aligned(4))) float f32x2a;  // 4B-aligned float2

#define HH 96
#define WW 96
#define HWSZ 9216
#define CI 256
#define CO 256
#define NB 2
#define NPIX 18432           // NB*HWSZ
#define KTOT 2304            // CI*9
#define BM 256
#define BN 32
#define BK 32
#define NCHUNK 72            // KTOT/BK

__device__ __forceinline__ ushort_t f2bf(float f) {
  unsigned int u = __float_as_uint(f);
  u += 0x7fffu + ((u >> 16) & 1u);   // RNE
  return (ushort_t)(u >> 16);
}

__device__ __forceinline__ void gload16(const void* g, void* l) {
  __builtin_amdgcn_global_load_lds(
      (const __attribute__((address_space(1))) unsigned int*)g,
      (__attribute__((address_space(3))) unsigned int*)l, 16, 0, 0);
}

// ---------------- 1a) w_dcn -> bf16, reordered per-chunk [ko][kg][m][8] ----------------
__global__ void cvt_w9(const float* __restrict__ w, ushort_t* __restrict__ o) {
  int i = blockIdx.x * 256 + threadIdx.x;     // i = oo*KTOT + kk, grid exact (CO*KTOT)
  int oo = i / KTOT;
  int kk = i - oo * KTOT;
  int ko = kk >> 5, kg = (kk >> 3) & 3, j = kk & 7;
  o[ko * 8192 + kg * 2048 + oo * 8 + j] = f2bf(w[i]);
}

// ---------------- 1b) w_off [ch][ci][t] -> [ci][ch*9+t] ----------------
__global__ void cvt_wofft(const float* __restrict__ w, float* __restrict__ o) {
  int i = blockIdx.x * 256 + threadIdx.x;     // exact: 27*2304 = 62208
  int ch = i / 2304;
  int r = i - ch * 2304;
  int ci = r / 9, t = r - ci * 9;
  o[ci * 243 + ch * 9 + t] = w[i];
}

// ---------------- 2) offset conv partials ----------------
// om_part layout: [4 part][27 ch][NPIX]. Block: 64 px x 4 subs of 16 ci; LDS reduce.
__global__ __launch_bounds__(256, 4) void off_conv_part(
    const float* __restrict__ x, const float* __restrict__ w_offt,
    float* __restrict__ om_part) {
  const int tid = threadIdx.x;
  const int px = tid & 63, sub = tid >> 6;
  const int n = blockIdx.x * 64 + px;          // grid.x = NPIX/64 = 288
  const int part = blockIdx.y;                  // 0..3
  const int b = n / HWSZ;
  const int hw = n - b * HWSZ;
  const int h = hw / WW, w = hw - h * WW;
  float acc[27];
#pragma unroll
  for (int i = 0; i < 27; ++i) acc[i] = 0.f;
  const float* xp = x + (size_t)b * CI * HWSZ + hw;
  const bool okr0 = h > 0, okr2 = h < HH - 1;
  const bool okc0 = w > 0, okc2 = w < WW - 1;
  const int ci0 = part * 64 + sub * 16;
  for (int ci = ci0; ci < ci0 + 16; ++ci) {
    const float* xc = xp + (size_t)ci * HWSZ;
    float xv[9];
#pragma unroll
    for (int t = 0; t < 9; ++t) {
      int dy = t / 3 - 1, dx = t % 3 - 1;
      bool ok = (dy == 0 || (dy < 0 ? okr0 : okr2)) && (dx == 0 || (dx < 0 ? okc0 : okc2));
      xv[t] = ok ? xc[dy * WW + dx] : 0.f;
    }
    const float* wp = w_offt + ci * 243;       // uniform -> scalar loads
#pragma unroll
    for (int ch = 0; ch < 27; ++ch)
#pragma unroll
      for (int t = 0; t < 9; ++t) acc[ch] = fmaf(xv[t], wp[ch * 9 + t], acc[ch]);
  }
  __shared__ float red[4][27][64];              // 27.6 KB
#pragma unroll
  for (int ch = 0; ch < 27; ++ch) red[sub][ch][px] = acc[ch];
  __syncthreads();
  for (int e = tid; e < 27 * 64; e += 256) {
    int ch = e >> 6, p = e & 63;
    float s = red[0][ch][p] + red[1][ch][p] + red[2][ch][p] + red[3][ch][p];
    om_part[((size_t)part * 27 + ch) * NPIX + blockIdx.x * 64 + p] = s;
  }
}

// ---------------- 3) prep: coords -> row-pair offsets + folded weights (SoA [k][n]) ----------------
// offs[k][n] = (yc0*96+xa) | (yc1*96+xa)<<16 ; wts[k][n] = {wa0,wb0,wa1,wb1}
// so that sample = wa0*x[o0] + wb0*x[o0+1] + wa1*x[o1] + wb1*x[o1+1].
__global__ void prep_kernel(const float* __restrict__ om_part, const float* __restrict__ b_off,
                            uint_t* __restrict__ offs, float4* __restrict__ wts) {
  int n = blockIdx.x * 256 + threadIdx.x;
  float om[27];
#pragma unroll
  for (int ch = 0; ch < 27; ++ch) {
    float s = b_off[ch];
#pragma unroll
    for (int p = 0; p < 4; ++p)
      s += om_part[((size_t)p * 27 + ch) * NPIX + n];
    om[ch] = s;
  }
  int hw = n % HWSZ;
  int h = hw / WW;
  int w = hw - h * WW;
#pragma unroll
  for (int k = 0; k < 9; ++k) {
    float dy = om[2 * k];
    float dx = om[2 * k + 1];
    float mk = 1.f / (1.f + __expf(-om[18 + k]));
    float py = dy + (float)(h - 1 + k / 3);
    float px = dx + (float)(w - 1 + k % 3);
    float y0f = floorf(py), x0f = floorf(px);
    int y0 = (int)y0f, x0 = (int)x0f;
    float wy1 = py - y0f, wx1 = px - x0f;
    float wy0 = 1.f - wy1, wx0 = 1.f - wx1;
    float vy0 = (y0 >= 0 && y0 <= HH - 1) ? 1.f : 0.f;
    float vy1 = (y0 + 1 >= 0 && y0 + 1 <= HH - 1) ? 1.f : 0.f;
    int yc0 = min(max(y0, 0), HH - 1), yc1 = min(max(y0 + 1, 0), HH - 1);
    int xa = min(max(x0, 0), WW - 2);
    float a_, b_;
    if (x0 >= 0 && x0 <= WW - 2)      { a_ = wx0; b_ = wx1; }
    else if (x0 == -1)                { a_ = wx1; b_ = 0.f; }
    else if (x0 == WW - 1)            { a_ = 0.f; b_ = wx0; }
    else                              { a_ = 0.f; b_ = 0.f; }
    float s0 = mk * vy0 * wy0, s1 = mk * vy1 * wy1;
    offs[(size_t)k * NPIX + n] = (uint_t)(yc0 * WW + xa) | ((uint_t)(yc1 * WW + xa) << 16);
    wts[(size_t)k * NPIX + n] = make_float4(a_ * s0, b_ * s0, a_ * s1, b_ * s1);
  }
}

// ---------------- 4) fused sample + GEMM ----------------
// out[b,o,hw] = sum_kk W9[o,kk] * S[kk,n]. Grid: 576 N-tiles (BN=32), BM=256.
// 512 threads = 8 waves, wave tile 64x16. Double-buffered LDS, 1-deep prefetch.
__global__ __launch_bounds__(512, 4) void dcn_gemm(
    const float* __restrict__ x, const ushort_t* __restrict__ w9r,
    const uint_t* __restrict__ offs, const float4* __restrict__ wts,
    const float* __restrict__ b_dcn, float* __restrict__ out) {
  __shared__ __align__(16) ushort_t Alds[2][8192];   // [buf][kg][256][8] = 32 KB
  __shared__ __align__(16) ushort_t Slds[2][1024];   // [buf][kg][32][8]  = 4 KB
  __shared__ uint_t off_l[9][32];
  __shared__ __align__(16) float4 wt_l[9][32];

  const int tid = threadIdx.x;
  const int p0 = blockIdx.x * BN;             // grid.x = 576
  const int bimg = p0 / HWSZ;                 // uniform per tile
  const int hw0 = p0 - bimg * HWSZ;
  const float* xb = x + (size_t)bimg * CI * HWSZ;

  for (int e = tid; e < 9 * BN; e += 512) {
    int k = e >> 5, p = e & 31;
    off_l[k][p] = offs[(size_t)k * NPIX + p0 + p];
    wt_l[k][p] = wts[(size_t)k * NPIX + p0 + p];
  }

  f32x4 acc[4];
#pragma unroll
  for (int i = 0; i < 4; ++i) acc[i] = (f32x4){0.f, 0.f, 0.f, 0.f};

  const int lane = tid & 63, wid = tid >> 6;
  const int wr = wid >> 1, wc = wid & 1;      // wave tile: rows wr*64, cols wc*16
  const int lg = lane >> 4, lm = lane & 15;
  const int sp = tid & 31;                    // pixel within tile
  const int sk2 = tid >> 5;                   // 0..15 -> kk pair
  int kb, cb;
  { int kkb = sk2 * 2; cb = kkb / 9; kb = kkb - cb * 9; }

  __syncthreads();  // prep tables visible

  // ---- prologue: prefetch chunk 0 ----
  f32x2a r0[2], r1[2];
  {
    int c = cb, k = kb;
#pragma unroll
    for (int j = 0; j < 2; ++j) {
      uint_t o2 = off_l[k][sp];
      const float* xc = xb + c * HWSZ;
      r0[j] = *(const f32x2a*)(xc + (o2 & 0xffffu));
      r1[j] = *(const f32x2a*)(xc + (o2 >> 16));
      ++k; if (k == 9) { k = 0; ++c; }
    }
    const ushort_t* ga = w9r + tid * 8;
    gload16(ga, &Alds[0][wid * 512]);
    gload16(ga + 4096, &Alds[0][4096 + wid * 512]);
  }

  for (int ko = 0; ko < NCHUNK; ++ko) {
    const int cur = ko & 1, nxt = cur ^ 1;
    // ---- consume prefetched gathers -> S values -> LDS[cur] ----
    {
      float v[2];
      int k = kb;
#pragma unroll
      for (int j = 0; j < 2; ++j) {
        float4 wv = wt_l[k][sp];
        v[j] = wv.x * r0[j].x + wv.y * r0[j].y + wv.z * r1[j].x + wv.w * r1[j].y;
        ++k; if (k == 9) k = 0;
      }
      uint_t pk = (uint_t)f2bf(v[0]) | ((uint_t)f2bf(v[1]) << 16);
      *(uint_t*)&Slds[cur][((sk2 >> 2) * 32 + sp) * 8 + (sk2 & 3) * 2] = pk;
    }
    // ---- prefetch chunk ko+1 (regs + A stage into [nxt]) ----
    if (ko < NCHUNK - 1) {
      kb += 5; cb += 3;
      if (kb >= 9) { kb -= 9; ++cb; }
      int c = cb, k = kb;
#pragma unroll
      for (int j = 0; j < 2; ++j) {
        uint_t o2 = off_l[k][sp];
        const float* xc = xb + c * HWSZ;
        r0[j] = *(const f32x2a*)(xc + (o2 & 0xffffu));
        r1[j] = *(const f32x2a*)(xc + (o2 >> 16));
        ++k; if (k == 9) { k = 0; ++c; }
      }
      const ushort_t* ga = w9r + (size_t)(ko + 1) * 8192 + tid * 8;
      gload16(ga, &Alds[nxt][wid * 512]);
      gload16(ga + 4096, &Alds[nxt][4096 + wid * 512]);
    }
    __syncthreads();   // S[cur] visible; A[cur] + reg prefetch drained
    // ---- MFMA on [cur] ----
    bf16x8 bfr = *(const bf16x8*)&Slds[cur][(lg * 32 + wc * 16 + lm) * 8];
#pragma unroll
    for (int mi = 0; mi < 4; ++mi) {
      bf16x8 af = *(const bf16x8*)&Alds[cur][(lg * 256 + wr * 64 + mi * 16 + lm) * 8];
      acc[mi] = __builtin_amdgcn_mfma_f32_16x16x32_bf16(af, bfr, acc[mi], 0, 0, 0);
    }
    __syncthreads();   // reads done before next iter overwrites [cur]-adjacent buffers
  }

  // ---- epilogue: + b_dcn, store pre-BN fp32 ----
  const int hwv = hw0 + wc * 16 + lm;
#pragma unroll
  for (int mi = 0; mi < 4; ++mi) {
    int obase = wr * 64 + mi * 16 + lg * 4;
#pragma unroll
    for (int r = 0; r < 4; ++r) {
      int o = obase + r;
      out[((size_t)(bimg * CO + o)) * HWSZ + hwv] = acc[mi][r] + b_dcn[o];
    }
  }
}

// ---------------- 5) BN stats ----------------
__global__ void bn_stats(const float* __restrict__ out, const float* __restrict__ gamma,
                         const float* __restrict__ beta, float* __restrict__ ss) {
  int o = blockIdx.x;
  int tid = threadIdx.x;
  float s = 0.f, sq = 0.f;
#pragma unroll
  for (int b = 0; b < NB; ++b) {
    const float4* p = (const float4*)(out + ((size_t)(b * CO + o)) * HWSZ);
    for (int j = tid; j < HWSZ / 4; j += 256) {
      float4 v = p[j];
      s += v.x + v.y + v.z + v.w;
      sq += v.x * v.x + v.y * v.y + v.z * v.z + v.w * v.w;
    }
  }
#pragma unroll
  for (int off = 32; off > 0; off >>= 1) {
    s += __shfl_xor(s, off);
    sq += __shfl_xor(sq, off);
  }
  __shared__ float rs[4], rq[4];
  if ((tid & 63) == 0) { rs[tid >> 6] = s; rq[tid >> 6] = sq; }
  __syncthreads();
  if (tid == 0) {
    s = rs[0] + rs[1] + rs[2] + rs[3];
    sq = rq[0] + rq[1] + rq[2] + rq[3];
    float mean = s * (1.f / (float)NPIX);
    float var = sq * (1.f / (float)NPIX) - mean * mean;
    float rstd = rsqrtf(var + 1e-5f);
    float sc = rstd * gamma[o];
    ss[o] = sc;
    ss[CO + o] = beta[o] - mean * sc;
  }
}

// ---------------- 6) BN apply + ReLU ----------------
__global__ void bn_apply(float* __restrict__ out, const float* __restrict__ ss) {
  int i = blockIdx.x * 256 + threadIdx.x;  // float4 index, exact grid
  float4 v = ((float4*)out)[i];
  int o = (i / (HWSZ / 4)) & 255;
  float sc = ss[o], sh = ss[CO + o];
  v.x = fmaxf(v.x * sc + sh, 0.f);
  v.y = fmaxf(v.y * sc + sh, 0.f);
  v.z = fmaxf(v.z * sc + sh, 0.f);
  v.w = fmaxf(v.w * sc + sh, 0.f);
  ((float4*)out)[i] = v;
}

extern "C" void kernel_launch(void* const* d_in, const int* in_sizes, int n_in,
                              void* d_out, int out_size, void* d_ws, size_t ws_size,
                              hipStream_t stream) {
  const float* x = (const float*)d_in[0];
  const float* w_off = (const float*)d_in[1];
  const float* b_off = (const float*)d_in[2];
  const float* w_dcn = (const float*)d_in[3];
  const float* b_dcn = (const float*)d_in[4];
  const float* gamma = (const float*)d_in[5];
  const float* beta = (const float*)d_in[6];
  float* out = (float*)d_out;

  // ws layout (bytes): total ~12.7 MB
  char* ws = (char*)d_ws;
  float* om_part = (float*)(ws);                         // 4*27*18432*4 = 7,962,624 B
  uint_t* offs = (uint_t*)(ws + 7962624);                // 9*18432*4  =   663,552 B
  float4* wts = (float4*)(ws + 8626176);                 // 9*18432*16 = 2,654,208 B
  ushort_t* w9r = (ushort_t*)(ws + 11280384);            // 2304*256*2 = 1,179,648 B
  float* ss = (float*)(ws + 12460032);                   // 512 f = 2,048 B
  float* w_offt = (float*)(ws + 12462080);               // 256*243*4 =   248,832 B

  cvt_w9<<<(CO * KTOT) / 256, 256, 0, stream>>>(w_dcn, w9r);
  cvt_wofft<<<(27 * KTOT) / 256, 256, 0, stream>>>(w_off, w_offt);
  off_conv_part<<<dim3(NPIX / 64, 4), 256, 0, stream>>>(x, w_offt, om_part);
  prep_kernel<<<NPIX / 256, 256, 0, stream>>>(om_part, b_off, offs, wts);
  dcn_gemm<<<NPIX / BN, 512, 0, stream>>>(x, w9r, offs, wts, b_dcn, out);
  bn_stats<<<CO, 256, 0, stream>>>(out, gamma, beta, ss);
  bn_apply<<<(out_size / 4) / 256, 256, 0, stream>>>(out, ss);
}

// Round 5
// 247.198 us; speedup vs baseline: 1.3442x; 1.3442x over previous
//
#include <hip/hip_runtime.h>

// DeformConv fused pipeline, MI355X gfx950.
// Shapes (hard-coded per reference): B=2, Ci=Co=256, H=W=96.
// R5 changes vs R4:
//  - off_conv3: wave-per-channel-group (7 ch/wave), weights via scalar loads
//    (readfirstlane base), xv prefetch, 2 ci-parts, no LDS reduce.
//  - dcn_gemm: raw s_barrier + counted s_waitcnt vmcnt(6) -> prefetch survives
//    the barrier (T3/T4); single S buffer; last chunk peeled with vmcnt(0).

typedef unsigned short ushort_t;
typedef unsigned int uint_t;
typedef __attribute__((ext_vector_type(8))) short bf16x8;
typedef __attribute__((ext_vector_type(4))) float f32x4;
typedef __attribute__((ext_vector_type(2), aligned(4))) float f32x2a;  // 4B-aligned float2

#define HH 96
#define WW 96
#define HWSZ 9216
#define CI 256
#define CO 256
#define NB 2
#define NPIX 18432           // NB*HWSZ
#define KTOT 2304            // CI*9
#define BM 256
#define BN 32
#define BK 32
#define NCHUNK 72            // KTOT/BK

__device__ __forceinline__ ushort_t f2bf(float f) {
  unsigned int u = __float_as_uint(f);
  u += 0x7fffu + ((u >> 16) & 1u);   // RNE
  return (ushort_t)(u >> 16);
}

__device__ __forceinline__ void gload16(const void* g, void* l) {
  __builtin_amdgcn_global_load_lds(
      (const __attribute__((address_space(1))) unsigned int*)g,
      (__attribute__((address_space(3))) unsigned int*)l, 16, 0, 0);
}

// ---------------- 1a) w_dcn -> bf16, reordered per-chunk [ko][kg][m][8] ----------------
__global__ void cvt_w9(const float* __restrict__ w, ushort_t* __restrict__ o) {
  int i = blockIdx.x * 256 + threadIdx.x;     // i = oo*KTOT + kk, grid exact (CO*KTOT)
  int oo = i / KTOT;
  int kk = i - oo * KTOT;
  int ko = kk >> 5, kg = (kk >> 3) & 3, j = kk & 7;
  o[ko * 8192 + kg * 2048 + oo * 8 + j] = f2bf(w[i]);
}

// ---------------- 1b) w_off [ch][ci][t] -> [ci][ch*9+t] ----------------
__global__ void cvt_wofft(const float* __restrict__ w, float* __restrict__ o) {
  int i = blockIdx.x * 256 + threadIdx.x;     // exact: 27*2304 = 62208
  int ch = i / 2304;
  int r = i - ch * 2304;
  int ci = r / 9, t = r - ci * 9;
  o[ci * 243 + ch * 9 + t] = w[i];
}

// ---------------- 2) offset conv: wave-per-channel-group ----------------
// om_part layout: [2 part][27 ch][NPIX]. Block = 64 px x 4 waves; wave w owns
// channels [7w, 7w+7) (wave 3: 6). Weights are wave-uniform -> scalar loads.
__global__ __launch_bounds__(256, 4) void off_conv3(
    const float* __restrict__ x, const float* __restrict__ w_offt,
    float* __restrict__ om_part) {
  const int tid = threadIdx.x;
  const int lane = tid & 63;
  const int wid = __builtin_amdgcn_readfirstlane(tid >> 6);
  const int n = blockIdx.x * 64 + lane;        // grid.x = NPIX/64 = 288
  const int part = blockIdx.y;                  // 0..1 -> 128 ci each
  const int b = n / HWSZ;
  const int hw = n - b * HWSZ;
  const int h = hw / WW, w = hw - h * WW;
  const float* xp = x + (size_t)b * CI * HWSZ + hw;

  int soff[9]; float msk[9];
#pragma unroll
  for (int t = 0; t < 9; ++t) {
    int dy = t / 3 - 1, dx = t % 3 - 1;
    bool ok = (h + dy >= 0) && (h + dy < HH) && (w + dx >= 0) && (w + dx < WW);
    soff[t] = ok ? dy * WW + dx : 0;
    msk[t] = ok ? 1.f : 0.f;
  }

  const int ch0 = wid * 7;
  const int nch = (wid < 3) ? 7 : 6;
  float acc[7];
#pragma unroll
  for (int i = 0; i < 7; ++i) acc[i] = 0.f;

  const int ci0 = part * 128;
  const float* wbase = w_offt + ch0 * 9;
  float xv[9];
  {
    const float* xc = xp + (size_t)ci0 * HWSZ;
#pragma unroll
    for (int t = 0; t < 9; ++t) xv[t] = xc[soff[t]] * msk[t];
  }
  for (int ci = ci0; ci < ci0 + 128; ++ci) {
    float xn[9];
    {
      int cin = (ci + 1 < ci0 + 128) ? ci + 1 : ci;   // last iter reloads self
      const float* xc = xp + (size_t)cin * HWSZ;
#pragma unroll
      for (int t = 0; t < 9; ++t) xn[t] = xc[soff[t]] * msk[t];
    }
    const float* wp = wbase + ci * 243;          // wave-uniform -> s_load
#pragma unroll
    for (int ch = 0; ch < 7; ++ch)               // wave3 ch6 reads pad, discarded
#pragma unroll
      for (int t = 0; t < 9; ++t)
        acc[ch] = fmaf(xv[t], wp[ch * 9 + t], acc[ch]);
#pragma unroll
    for (int t = 0; t < 9; ++t) xv[t] = xn[t];
  }
#pragma unroll
  for (int ch = 0; ch < 7; ++ch)
    if (ch < nch)
      om_part[((size_t)(part * 27 + ch0 + ch)) * NPIX + n] = acc[ch];
}

// ---------------- 3) prep: coords -> row-pair offsets + folded weights (SoA [k][n]) ----------------
// offs[k][n] = (yc0*96+xa) | (yc1*96+xa)<<16 ; wts[k][n] = {wa0,wb0,wa1,wb1}
// so that sample = wa0*x[o0] + wb0*x[o0+1] + wa1*x[o1] + wb1*x[o1+1].
__global__ void prep_kernel(const float* __restrict__ om_part, const float* __restrict__ b_off,
                            uint_t* __restrict__ offs, float4* __restrict__ wts) {
  int n = blockIdx.x * 128 + threadIdx.x;       // grid 144 x 128
  float om[27];
#pragma unroll
  for (int ch = 0; ch < 27; ++ch) {
    float s = b_off[ch];
#pragma unroll
    for (int p = 0; p < 2; ++p)
      s += om_part[((size_t)p * 27 + ch) * NPIX + n];
    om[ch] = s;
  }
  int hw = n % HWSZ;
  int h = hw / WW;
  int w = hw - h * WW;
#pragma unroll
  for (int k = 0; k < 9; ++k) {
    float dy = om[2 * k];
    float dx = om[2 * k + 1];
    float mk = 1.f / (1.f + __expf(-om[18 + k]));
    float py = dy + (float)(h - 1 + k / 3);
    float px = dx + (float)(w - 1 + k % 3);
    float y0f = floorf(py), x0f = floorf(px);
    int y0 = (int)y0f, x0 = (int)x0f;
    float wy1 = py - y0f, wx1 = px - x0f;
    float wy0 = 1.f - wy1, wx0 = 1.f - wx1;
    float vy0 = (y0 >= 0 && y0 <= HH - 1) ? 1.f : 0.f;
    float vy1 = (y0 + 1 >= 0 && y0 + 1 <= HH - 1) ? 1.f : 0.f;
    int yc0 = min(max(y0, 0), HH - 1), yc1 = min(max(y0 + 1, 0), HH - 1);
    int xa = min(max(x0, 0), WW - 2);
    float a_, b_;
    if (x0 >= 0 && x0 <= WW - 2)      { a_ = wx0; b_ = wx1; }
    else if (x0 == -1)                { a_ = wx1; b_ = 0.f; }
    else if (x0 == WW - 1)            { a_ = 0.f; b_ = wx0; }
    else                              { a_ = 0.f; b_ = 0.f; }
    float s0 = mk * vy0 * wy0, s1 = mk * vy1 * wy1;
    offs[(size_t)k * NPIX + n] = (uint_t)(yc0 * WW + xa) | ((uint_t)(yc1 * WW + xa) << 16);
    wts[(size_t)k * NPIX + n] = make_float4(a_ * s0, b_ * s0, a_ * s1, b_ * s1);
  }
}

// ---------------- 4) fused sample + GEMM ----------------
// out[b,o,hw] = sum_kk W9[o,kk] * S[kk,n]. Grid: 576 N-tiles (BN=32), BM=256.
// 512 threads = 8 waves, wave tile 64x16. Counted-vmcnt pipeline:
// prefetch (4 gathers + 2 gload_lds) stays in flight across raw s_barrier.
__global__ __launch_bounds__(512, 4) void dcn_gemm(
    const float* __restrict__ x, const ushort_t* __restrict__ w9r,
    const uint_t* __restrict__ offs, const float4* __restrict__ wts,
    const float* __restrict__ b_dcn, float* __restrict__ out) {
  __shared__ __align__(16) ushort_t Alds[2][8192];   // [buf][kg][256][8] = 32 KB
  __shared__ __align__(16) ushort_t Slds[1024];      // [kg][32][8] = 2 KB (single buf)
  __shared__ uint_t off_l[9][32];
  __shared__ __align__(16) float4 wt_l[9][32];

  const int tid = threadIdx.x;
  const int p0 = blockIdx.x * BN;             // grid.x = 576
  const int bimg = p0 / HWSZ;                 // uniform per tile
  const int hw0 = p0 - bimg * HWSZ;
  const float* xb = x + (size_t)bimg * CI * HWSZ;

  for (int e = tid; e < 9 * BN; e += 512) {
    int k = e >> 5, p = e & 31;
    off_l[k][p] = offs[(size_t)k * NPIX + p0 + p];
    wt_l[k][p] = wts[(size_t)k * NPIX + p0 + p];
  }

  f32x4 acc[4];
#pragma unroll
  for (int i = 0; i < 4; ++i) acc[i] = (f32x4){0.f, 0.f, 0.f, 0.f};

  const int lane = tid & 63, wid = tid >> 6;
  const int wr = wid >> 1, wc = wid & 1;      // wave tile: rows wr*64, cols wc*16
  const int lg = lane >> 4, lm = lane & 15;
  const int sp = tid & 31;                    // pixel within tile
  const int sk2 = tid >> 5;                   // 0..15 -> kk pair
  int cb, kb;
  { int kkb = sk2 * 2; cb = kkb / 9; kb = kkb - cb * 9; }

  __syncthreads();  // prep tables visible

  // ---- prologue: issue chunk 0 (4 gathers + A[0] stage) ----
  f32x2a r0[2], r1[2];
  {
    int c = cb, k = kb;
#pragma unroll
    for (int j = 0; j < 2; ++j) {
      uint_t o2 = off_l[k][sp];
      const float* xc = xb + c * HWSZ;
      r0[j] = *(const f32x2a*)(xc + (o2 & 0xffffu));
      r1[j] = *(const f32x2a*)(xc + (o2 >> 16));
      ++k; if (k == 9) { k = 0; ++c; }
    }
    const ushort_t* ga = w9r + tid * 8;
    gload16(ga, &Alds[0][wid * 512]);
    gload16(ga + 4096, &Alds[0][4096 + wid * 512]);
  }

  for (int ko = 0; ko < NCHUNK - 1; ++ko) {
    const int cur = ko & 1, nxt = cur ^ 1;
    // ---- consume prefetched gathers -> S values -> Slds ----
    {
      float v[2];
      int k = kb;
#pragma unroll
      for (int j = 0; j < 2; ++j) {
        float4 wv = wt_l[k][sp];
        v[j] = wv.x * r0[j].x + wv.y * r0[j].y + wv.z * r1[j].x + wv.w * r1[j].y;
        ++k; if (k == 9) k = 0;
      }
      uint_t pk = (uint_t)f2bf(v[0]) | ((uint_t)f2bf(v[1]) << 16);
      *(uint_t*)&Slds[((sk2 >> 2) * 32 + sp) * 8 + (sk2 & 3) * 2] = pk;
    }
    // ---- issue prefetch for chunk ko+1 (4 gathers + A[nxt] stage) ----
    {
      kb += 5; cb += 3;
      if (kb >= 9) { kb -= 9; ++cb; }
      int c = cb, k = kb;
#pragma unroll
      for (int j = 0; j < 2; ++j) {
        uint_t o2 = off_l[k][sp];
        const float* xc = xb + c * HWSZ;
        r0[j] = *(const f32x2a*)(xc + (o2 & 0xffffu));
        r1[j] = *(const f32x2a*)(xc + (o2 >> 16));
        ++k; if (k == 9) { k = 0; ++c; }
      }
      const ushort_t* ga = w9r + (size_t)(ko + 1) * 8192 + tid * 8;
      gload16(ga, &Alds[nxt][wid * 512]);
      gload16(ga + 4096, &Alds[nxt][4096 + wid * 512]);
    }
    // barrier 1: S visible, prev A landed; THIS chunk's 6 loads stay in flight
    asm volatile("s_waitcnt vmcnt(6) lgkmcnt(0)" ::: "memory");
    __builtin_amdgcn_s_barrier();
    asm volatile("" ::: "memory");
    // ---- MFMA on A[cur], S ----
    {
      bf16x8 bfr = *(const bf16x8*)&Slds[(lg * 32 + wc * 16 + lm) * 8];
#pragma unroll
      for (int mi = 0; mi < 4; ++mi) {
        bf16x8 af = *(const bf16x8*)&Alds[cur][(lg * 256 + wr * 64 + mi * 16 + lm) * 8];
        acc[mi] = __builtin_amdgcn_mfma_f32_16x16x32_bf16(af, bfr, acc[mi], 0, 0, 0);
      }
    }
    // barrier 2: LDS reads complete before next iter's writers
    asm volatile("s_waitcnt lgkmcnt(0)" ::: "memory");
    __builtin_amdgcn_s_barrier();
    asm volatile("" ::: "memory");
  }

  // ---- peeled last chunk (no prefetch; full drain) ----
  {
    const int cur = (NCHUNK - 1) & 1;
    {
      float v[2];
      int k = kb;
#pragma unroll
      for (int j = 0; j < 2; ++j) {
        float4 wv = wt_l[k][sp];
        v[j] = wv.x * r0[j].x + wv.y * r0[j].y + wv.z * r1[j].x + wv.w * r1[j].y;
        ++k; if (k == 9) k = 0;
      }
      uint_t pk = (uint_t)f2bf(v[0]) | ((uint_t)f2bf(v[1]) << 16);
      *(uint_t*)&Slds[((sk2 >> 2) * 32 + sp) * 8 + (sk2 & 3) * 2] = pk;
    }
    asm volatile("s_waitcnt vmcnt(0) lgkmcnt(0)" ::: "memory");
    __builtin_amdgcn_s_barrier();
    asm volatile("" ::: "memory");
    bf16x8 bfr = *(const bf16x8*)&Slds[(lg * 32 + wc * 16 + lm) * 8];
#pragma unroll
    for (int mi = 0; mi < 4; ++mi) {
      bf16x8 af = *(const bf16x8*)&Alds[cur][(lg * 256 + wr * 64 + mi * 16 + lm) * 8];
      acc[mi] = __builtin_amdgcn_mfma_f32_16x16x32_bf16(af, bfr, acc[mi], 0, 0, 0);
    }
  }

  // ---- epilogue: + b_dcn, store pre-BN fp32 ----
  const int hwv = hw0 + wc * 16 + lm;
#pragma unroll
  for (int mi = 0; mi < 4; ++mi) {
    int obase = wr * 64 + mi * 16 + lg * 4;
#pragma unroll
    for (int r = 0; r < 4; ++r) {
      int o = obase + r;
      out[((size_t)(bimg * CO + o)) * HWSZ + hwv] = acc[mi][r] + b_dcn[o];
    }
  }
}

// ---------------- 5) BN stats ----------------
__global__ void bn_stats(const float* __restrict__ out, const float* __restrict__ gamma,
                         const float* __restrict__ beta, float* __restrict__ ss) {
  int o = blockIdx.x;
  int tid = threadIdx.x;
  float s = 0.f, sq = 0.f;
#pragma unroll
  for (int b = 0; b < NB; ++b) {
    const float4* p = (const float4*)(out + ((size_t)(b * CO + o)) * HWSZ);
    for (int j = tid; j < HWSZ / 4; j += 256) {
      float4 v = p[j];
      s += v.x + v.y + v.z + v.w;
      sq += v.x * v.x + v.y * v.y + v.z * v.z + v.w * v.w;
    }
  }
#pragma unroll
  for (int off = 32; off > 0; off >>= 1) {
    s += __shfl_xor(s, off);
    sq += __shfl_xor(sq, off);
  }
  __shared__ float rs[4], rq[4];
  if ((tid & 63) == 0) { rs[tid >> 6] = s; rq[tid >> 6] = sq; }
  __syncthreads();
  if (tid == 0) {
    s = rs[0] + rs[1] + rs[2] + rs[3];
    sq = rq[0] + rq[1] + rq[2] + rq[3];
    float mean = s * (1.f / (float)NPIX);
    float var = sq * (1.f / (float)NPIX) - mean * mean;
    float rstd = rsqrtf(var + 1e-5f);
    float sc = rstd * gamma[o];
    ss[o] = sc;
    ss[CO + o] = beta[o] - mean * sc;
  }
}

// ---------------- 6) BN apply + ReLU ----------------
__global__ void bn_apply(float* __restrict__ out, const float* __restrict__ ss) {
  int i = blockIdx.x * 256 + threadIdx.x;  // float4 index, exact grid
  float4 v = ((float4*)out)[i];
  int o = (i / (HWSZ / 4)) & 255;
  float sc = ss[o], sh = ss[CO + o];
  v.x = fmaxf(v.x * sc + sh, 0.f);
  v.y = fmaxf(v.y * sc + sh, 0.f);
  v.z = fmaxf(v.z * sc + sh, 0.f);
  v.w = fmaxf(v.w * sc + sh, 0.f);
  ((float4*)out)[i] = v;
}

extern "C" void kernel_launch(void* const* d_in, const int* in_sizes, int n_in,
                              void* d_out, int out_size, void* d_ws, size_t ws_size,
                              hipStream_t stream) {
  const float* x = (const float*)d_in[0];
  const float* w_off = (const float*)d_in[1];
  const float* b_off = (const float*)d_in[2];
  const float* w_dcn = (const float*)d_in[3];
  const float* b_dcn = (const float*)d_in[4];
  const float* gamma = (const float*)d_in[5];
  const float* beta = (const float*)d_in[6];
  float* out = (float*)d_out;

  // ws layout (bytes): total ~8.73 MB (previously proven >=13.1 MB available)
  char* ws = (char*)d_ws;
  float* om_part = (float*)(ws);                         // 2*27*18432*4 = 3,981,312 B
  uint_t* offs = (uint_t*)(ws + 3981312);                // 9*18432*4  =   663,552 B
  float4* wts = (float4*)(ws + 4644864);                 // 9*18432*16 = 2,654,208 B
  ushort_t* w9r = (ushort_t*)(ws + 7299072);             // 2304*256*2 = 1,179,648 B
  float* w_offt = (float*)(ws + 8478720);                // 256*243*4 + 1KB pad
  float* ss = (float*)(ws + 8728576);                    // 512 f

  cvt_w9<<<(CO * KTOT) / 256, 256, 0, stream>>>(w_dcn, w9r);
  cvt_wofft<<<(27 * KTOT) / 256, 256, 0, stream>>>(w_off, w_offt);
  off_conv3<<<dim3(NPIX / 64, 2), 256, 0, stream>>>(x, w_offt, om_part);
  prep_kernel<<<NPIX / 128, 128, 0, stream>>>(om_part, b_off, offs, wts);
  dcn_gemm<<<NPIX / BN, 512, 0, stream>>>(x, w9r, offs, wts, b_dcn, out);
  bn_stats<<<CO, 256, 0, stream>>>(out, gamma, beta, ss);
  bn_apply<<<(out_size / 4) / 256, 256, 0, stream>>>(out, ss);
}